// Round 7
// baseline (507.909 us; speedup 1.0000x reference)
//
#include <hip/hip_runtime.h>

// Attention_25855703122265: B=2, S=2048, D=2048, H=16, hd=128, causal prefill.
// fp32 I/O; bf16 MFMA compute.
//
// Round 12 = round 11 resubmitted (container infra failure, no verdict;
// hang-audit clean: uniform barriers, LDS 67584x2 fits, bounds ok):
//  - GEMMs: round-8 core (measured 141.9us qkv).
//  - attn_fwd v4: 256 thr / 4 waves x 32 q-rows (halves LDS-read:MFMA ratio
//    vs v3's 16-row waves), v3 staging kept (bf16 gld16 + XOR swizzle).
//    Grid 512 blocks (one 128-row q-tile each), qt = pair-map so co-resident
//    blocks (b, b+256) sum to 17 iters; 66KB LDS -> 2 blocks/CU overlap.
//
// Memory map:
//  d_out (fp32): a [0,8.39M) | k present [8.39M,16.78M) | v [16.78M,25.17M)
//    a-region reused as scratch until proj: xb bf16 @ bytes [0,16.78M),
//    q bf16 @ bytes [16.78M,33.55M)  (dead before proj GEMM writes a).
//  d_ws (83.9 MB): wt_q|wt_k|wt_v|wt_d (bf16 [N,K], 8.39MB each)
//    | attn_ws bf16 16.78MB | kb_ws bf16 16.78MB | vt_ws bf16 16.78MB

typedef unsigned short ushort_t;
typedef __attribute__((ext_vector_type(8))) short short8;   // 8 x bf16
typedef __attribute__((ext_vector_type(4))) float f32x4;

#define MFMA16x16x32 __builtin_amdgcn_mfma_f32_16x16x32_bf16
#define S_LEN   2048
#define DMODEL  2048
#define A_ELEMS 8388608   // B*S*D
#define W_ELEMS 4194304   // D*D

__device__ __forceinline__ ushort_t f2bf(float x) {
  unsigned u = __float_as_uint(x);
  u += 0x7FFFu + ((u >> 16) & 1u);
  return (ushort_t)(u >> 16);
}
__device__ __forceinline__ unsigned pack2(float lo, float hi) {
  return (unsigned)f2bf(lo) | ((unsigned)f2bf(hi) << 16);
}
struct f8 { float v[8]; };
__device__ __forceinline__ f8 ld8f(const float* p) {
  f8 r;
  float4 a = *(const float4*)p, b = *(const float4*)(p + 4);
  r.v[0]=a.x; r.v[1]=a.y; r.v[2]=a.z; r.v[3]=a.w;
  r.v[4]=b.x; r.v[5]=b.y; r.v[6]=b.z; r.v[7]=b.w;
  return r;
}
__device__ __forceinline__ uint4 cvt8(const f8& f) {
  uint4 o;
  o.x = pack2(f.v[0], f.v[1]); o.y = pack2(f.v[2], f.v[3]);
  o.z = pack2(f.v[4], f.v[5]); o.w = pack2(f.v[6], f.v[7]);
  return o;
}

// async global->LDS, 16B/lane; dest = wave-uniform base + lane*16
typedef const __attribute__((address_space(1))) void* gas_t;
typedef __attribute__((address_space(3))) void* las_t;
__device__ __forceinline__ void gld16(const void* g, void* l) {
  __builtin_amdgcn_global_load_lds((gas_t)(unsigned long long)g,
                                   (las_t)(unsigned)(unsigned long long)l,
                                   16, 0, 0);
}

// ---------------------------------------------------------------------------
// Prepass 1: x fp32 -> xb bf16 (straight convert, 8 elems/thread)
// ---------------------------------------------------------------------------
__global__ void __launch_bounds__(256) conv_x(const float* __restrict__ x,
                                              ushort_t* __restrict__ xb) {
  const int i = (blockIdx.x * 256 + threadIdx.x) * 8;
  f8 v = ld8f(x + i);
  *(uint4*)&xb[i] = cvt8(v);
}

// ---------------------------------------------------------------------------
// Prepass 2: W fp32 [K,N] -> wt bf16 [N,K]; 64x64 tiles; z picks weight
// ---------------------------------------------------------------------------
__global__ void __launch_bounds__(256) trans_w(
    const float* __restrict__ w0, const float* __restrict__ w1,
    const float* __restrict__ w2, const float* __restrict__ w3,
    ushort_t* __restrict__ o0, ushort_t* __restrict__ o1,
    ushort_t* __restrict__ o2, ushort_t* __restrict__ o3) {
  __shared__ float t[64][65];
  const float* src; ushort_t* dst;
  switch (blockIdx.z) {
    case 0: src = w0; dst = o0; break;
    case 1: src = w1; dst = o1; break;
    case 2: src = w2; dst = o2; break;
    default: src = w3; dst = o3; break;
  }
  const int kb = blockIdx.y * 64, nb = blockIdx.x * 64;
  const int r = threadIdx.x >> 3, c8 = (threadIdx.x & 7) * 8;
#pragma unroll
  for (int i = 0; i < 64; i += 32) {
    *(float4*)&t[r + i][c8]     = *(const float4*)&src[(size_t)(kb + r + i) * DMODEL + nb + c8];
    *(float4*)&t[r + i][c8 + 4] = *(const float4*)&src[(size_t)(kb + r + i) * DMODEL + nb + c8 + 4];
  }
  __syncthreads();
#pragma unroll
  for (int i = 0; i < 64; i += 32) {
    float tmp[8];
#pragma unroll
    for (int j = 0; j < 8; ++j) tmp[j] = t[c8 + j][r + i];
    uint4 o;
    o.x = pack2(tmp[0], tmp[1]); o.y = pack2(tmp[2], tmp[3]);
    o.z = pack2(tmp[4], tmp[5]); o.w = pack2(tmp[6], tmp[7]);
    *(uint4*)&dst[(size_t)(nb + r + i) * DMODEL + kb + c8] = o;
  }
}

// ---------------------------------------------------------------------------
// Prepass 3 (after gemm_qkv): v fp32 [B,H,S,128] -> vt bf16 [B,H,128,S]
// ---------------------------------------------------------------------------
__global__ void __launch_bounds__(256) trans_v(const float* __restrict__ v,
                                               ushort_t* __restrict__ vt) {
  __shared__ float t[64][65];
  const int bh = blockIdx.z;
  const int sb = blockIdx.x * 64, db = blockIdx.y * 64;
  const float* src = v + (size_t)bh * S_LEN * 128;
  ushort_t* dst = vt + (size_t)bh * 128 * S_LEN;
  const int r = threadIdx.x >> 3, c8 = (threadIdx.x & 7) * 8;
#pragma unroll
  for (int i = 0; i < 64; i += 32) {
    *(float4*)&t[r + i][c8]     = *(const float4*)&src[(size_t)(sb + r + i) * 128 + db + c8];
    *(float4*)&t[r + i][c8 + 4] = *(const float4*)&src[(size_t)(sb + r + i) * 128 + db + c8 + 4];
  }
  __syncthreads();
#pragma unroll
  for (int i = 0; i < 64; i += 32) {
    float tmp[8];
#pragma unroll
    for (int j = 0; j < 8; ++j) tmp[j] = t[c8 + j][r + i];
    uint4 o;
    o.x = pack2(tmp[0], tmp[1]); o.y = pack2(tmp[2], tmp[3]);
    o.z = pack2(tmp[4], tmp[5]); o.w = pack2(tmp[6], tmp[7]);
    *(uint4*)&dst[(size_t)(db + r + i) * S_LEN + sb + c8] = o;
  }
}

// ---------------------------------------------------------------------------
// 2-phase GEMM core (round-8, measured 141.9us qkv): C[128,256] tile, BK=64,
// 8 waves (2Mx4N, 64x64 per wave). LDS: A [2][2][128][32] (32KB) +
// B [2][2][256][32] (64KB) = 96KB. Slot-XOR swizzle both sides (0 conflicts).
// Per K-tile: 6 gld16 (tile start) + 2x{8 ds_read_b128 + 16 MFMA setprio}
// + one __syncthreads.  nt = 2048/64 = 32.
// ---------------------------------------------------------------------------
#define ABUF (2 * 128 * 32)   // elems per A double-buffer slot (16KB)
#define BBUF (2 * 256 * 32)   // elems per B double-buffer slot (32KB)

__device__ __forceinline__ void stage6(
    const ushort_t* __restrict__ gA, const ushort_t* __restrict__ gB,
    ushort_t* An, ushort_t* Bn, int t, int w, size_t soff) {
  const size_t kc = (size_t)t * 64;
#pragma unroll
  for (int i = 0; i < 2; ++i) {
    const int c = 2 * w + i, kh = c >> 3, rg = c & 7;
    gld16(gA + (size_t)(rg * 16) * 2048 + kc + kh * 32 + soff,
          An + (kh * 128 + rg * 16) * 32);
  }
#pragma unroll
  for (int i = 0; i < 4; ++i) {
    const int c = 4 * w + i, kh = c >> 4, rg = c & 15;
    gld16(gB + (size_t)(rg * 16) * 2048 + kc + kh * 32 + soff,
          Bn + (kh * 256 + rg * 16) * 32);
  }
}

__device__ __forceinline__ void gemm2p_core(
    const ushort_t* __restrict__ gA, const ushort_t* __restrict__ gB,
    ushort_t* AsF, ushort_t* BsF, int w, int lane, f32x4 acc[4][4]) {
  const int l15 = lane & 15, quad = lane >> 4;
  const int wm = w >> 2, wn = w & 3;
  const size_t soff = (size_t)(lane >> 2) * 2048 +
                      (((lane & 3) ^ ((lane >> 3) & 3)) * 8);
  const int rslot8 = (quad ^ ((l15 >> 1) & 3)) * 8;
  const int arow = wm * 64 + l15;
  const int brow = wn * 64 + l15;

  stage6(gA, gB, AsF, BsF, 0, w, soff);
  __syncthreads();

  for (int t = 0; t < 32; ++t) {
    ushort_t* Ab = AsF + (t & 1) * ABUF;
    ushort_t* Bb = BsF + (t & 1) * BBUF;
    if (t + 1 < 32)
      stage6(gA, gB, AsF + ((t + 1) & 1) * ABUF, BsF + ((t + 1) & 1) * BBUF,
             t + 1, w, soff);
#pragma unroll
    for (int kh = 0; kh < 2; ++kh) {
      short8 af[4], bf[4];
#pragma unroll
      for (int mi = 0; mi < 4; ++mi)
        af[mi] = *(const short8*)&Ab[(kh * 128 + arow + mi * 16) * 32 + rslot8];
#pragma unroll
      for (int ni = 0; ni < 4; ++ni)
        bf[ni] = *(const short8*)&Bb[(kh * 256 + brow + ni * 16) * 32 + rslot8];
      __builtin_amdgcn_s_setprio(1);
#pragma unroll
      for (int mi = 0; mi < 4; ++mi)
#pragma unroll
        for (int ni = 0; ni < 4; ++ni)
          acc[mi][ni] = MFMA16x16x32(af[mi], bf[ni], acc[mi][ni], 0, 0, 0);
      __builtin_amdgcn_s_setprio(0);
    }
    __syncthreads();
  }
}

// ---------------------------------------------------------------------------
// Fused QKV GEMM (2-phase core). 768 blocks = 3 exact CU rounds.
// XCD swizzle: logical = (bx&7)*96 + (bx>>3).
// ---------------------------------------------------------------------------
__global__ void __launch_bounds__(512, 2) gemm_qkv(
    const ushort_t* __restrict__ xb,
    const ushort_t* __restrict__ wtq, const ushort_t* __restrict__ wtk,
    const ushort_t* __restrict__ wtv,
    const float* __restrict__ bq, const float* __restrict__ bk,
    const float* __restrict__ bv,
    ushort_t* __restrict__ qout, float* __restrict__ kout,
    float* __restrict__ vout, ushort_t* __restrict__ kb16) {
  __shared__ ushort_t As_[2 * ABUF];   // 32KB
  __shared__ ushort_t Bs_[2 * BBUF];   // 64KB
  const int tid = threadIdx.x, w = tid >> 6, lane = tid & 63;
  const int l15 = lane & 15, quad = lane >> 4;
  const int wm = w >> 2, wn = w & 3;
  const int bx = blockIdx.x;
  const int logical = (bx & 7) * 96 + (bx >> 3);
  const int wid = logical >> 8, idx = logical & 255;
  const int tn = idx & 7, tm = idx >> 3;
  const ushort_t* Wt = wid == 0 ? wtq : (wid == 1 ? wtk : wtv);
  const float* bias = wid == 0 ? bq : (wid == 1 ? bk : bv);

  f32x4 acc[4][4] = {};
  gemm2p_core(xb + (size_t)(tm * 128) * 2048, Wt + (size_t)(tn * 256) * 2048,
              As_, Bs_, w, lane, acc);

  const int row0 = tm * 128 + wm * 64, col0 = tn * 256 + wn * 64;
#pragma unroll
  for (int ni = 0; ni < 4; ++ni) {
    const int col = col0 + ni * 16 + l15;
    const float bv_ = bias[col];
    const int h = col >> 7, d = col & 127;
#pragma unroll
    for (int mi = 0; mi < 4; ++mi) {
#pragma unroll
      for (int j = 0; j < 4; ++j) {
        const int row = row0 + mi * 16 + quad * 4 + j;
        const int b = row >> 11, s = row & 2047;
        const size_t idxg = (size_t)(((b * 16 + h) * 2048 + s)) * 128 + d;
        const float v = acc[mi][ni][j] + bv_;
        if (wid == 0) qout[idxg] = f2bf(v);
        else if (wid == 1) { kout[idxg] = v; kb16[idxg] = f2bf(v); }
        else vout[idxg] = v;
      }
    }
  }
}

// ---------------------------------------------------------------------------
// Proj GEMM (2-phase core): a[4096,2048] fp32 = attn_ws bf16 @ wt_d^T + bd
// 256 blocks = 1 exact CU round; logical = (bx&7)*32 + (bx>>3).
// ---------------------------------------------------------------------------
__global__ void __launch_bounds__(512, 2) gemm_proj(
    const ushort_t* __restrict__ A, const ushort_t* __restrict__ Wt,
    const float* __restrict__ bias, float* __restrict__ C) {
  __shared__ ushort_t As_[2 * ABUF];
  __shared__ ushort_t Bs_[2 * BBUF];
  const int tid = threadIdx.x, w = tid >> 6, lane = tid & 63;
  const int l15 = lane & 15, quad = lane >> 4;
  const int wm = w >> 2, wn = w & 3;
  const int logical = (blockIdx.x & 7) * 32 + (blockIdx.x >> 3);
  const int tn = logical & 7, tm = logical >> 3;

  f32x4 acc[4][4] = {};
  gemm2p_core(A + (size_t)(tm * 128) * 2048, Wt + (size_t)(tn * 256) * 2048,
              As_, Bs_, w, lane, acc);

  const int row0 = tm * 128 + wm * 64, col0 = tn * 256 + wn * 64;
#pragma unroll
  for (int ni = 0; ni < 4; ++ni) {
    const int col = col0 + ni * 16 + l15;
    const float bv_ = bias[col];
#pragma unroll
    for (int mi = 0; mi < 4; ++mi)
#pragma unroll
      for (int j = 0; j < 4; ++j) {
        const int row = row0 + mi * 16 + quad * 4 + j;
        C[(size_t)row * DMODEL + col] = acc[mi][ni][j] + bv_;
      }
  }
}

// ---------------------------------------------------------------------------
// Flash causal attention v4. 512 blocks x 256 thr (4 waves x 32 q-rows).
// Block bx: bh = bx & 31; t16 = bx >> 5; qt = t16<8 ? 15-t16 : t16-8
//   -> co-resident pair (bx, bx+256) gets qt {15-j, j}: 17 iters per CU.
// K/V^T staged via gld16 + XOR chunk swizzle (as v3); 66KB LDS, 2 blocks/CU.
// Per wave: 32 q-rows (mi 0..1) -> kf/vf fragment reads amortized 2x vs v3.
// ---------------------------------------------------------------------------
__global__ void __launch_bounds__(256, 2) attn_fwd(
    const ushort_t* __restrict__ Q, const ushort_t* __restrict__ Kb,
    const ushort_t* __restrict__ Vt, ushort_t* __restrict__ O) {
  __shared__ ushort_t KP[128 * 136];  // K tile [key][d] (linear 128x128) / Ps
  __shared__ ushort_t Vs[128 * 128];  // V^T tile [d][key] (linear, swizzled)
  const int tid = threadIdx.x;
  const int w = tid >> 6, lane = tid & 63;
  const int l15 = lane & 15, quad = lane >> 4;
  const int x7 = l15 & 7;                   // read-side swizzle term
  const int bh = blockIdx.x & 31, t16 = blockIdx.x >> 5;
  const int qt = (t16 < 8) ? (15 - t16) : (t16 - 8);
  const int b = bh >> 4, h = bh & 15;
  const size_t base  = (size_t)bh * (S_LEN * 128);  // Q,Kb: [bh][s][128]
  const size_t vbase = (size_t)bh * (128 * S_LEN);  // Vt:   [bh][d][s]
  const float cs = 0.08838834764831845f * 1.4426950408889634f;  // 1/sqrt(128)*log2(e)

  const int srow = lane >> 4;     // staging: row within 4-row group
  const int schunk = lane & 15;   // staging: 16B slot within 256B row

  const int q0 = qt * 128 + w * 32;   // this wave's first q row

  // Q fragments: A-layout A[m=l15][k=quad*8+j], mi = row-half
  short8 qf[2][4];
#pragma unroll
  for (int mi = 0; mi < 2; ++mi)
#pragma unroll
    for (int ks = 0; ks < 4; ++ks)
      qf[mi][ks] = *(const short8*)&Q[base +
          (size_t)(q0 + mi * 16 + l15) * 128 + ks * 32 + quad * 8];

  f32x4 oacc[2][8] = {};
  float mrun[2][4], lrun[2][4];
#pragma unroll
  for (int mi = 0; mi < 2; ++mi)
#pragma unroll
    for (int j = 0; j < 4; ++j) { mrun[mi][j] = -1e30f; lrun[mi][j] = 0.f; }

  for (int kt = 0; kt <= qt; ++kt) {
    const int kb_ = kt * 128;
    __syncthreads();  // prev iter's Ps/Vs reads done; buffers free
    // stage K rows and V^T rows: 8 chunks of 4 rows per wave (w*32 span)
#pragma unroll
    for (int i = 0; i < 8; ++i) {
      const int r = w * 32 + i * 4 + srow;
      const int c = schunk ^ (r & 7);           // pre-swizzled source chunk
      gld16(Kb + base + (size_t)(kb_ + r) * 128 + c * 8,
            (void*)(KP + (w * 32 + i * 4) * 128));
      gld16(Vt + vbase + (size_t)r * S_LEN + kb_ + c * 8,
            (void*)(Vs + (w * 32 + i * 4) * 128));
    }
    __syncthreads();  // drains vmcnt; staged data ready

    // S = Q K^T over 128 keys
    f32x4 sacc[2][8] = {};
#pragma unroll
    for (int ks = 0; ks < 4; ++ks) {
      const int sw = ((ks * 4 + quad) ^ x7) * 8;  // swizzled chunk offset
      short8 kf[8];
#pragma unroll
      for (int ni = 0; ni < 8; ++ni)
        kf[ni] = *(const short8*)&KP[(ni * 16 + l15) * 128 + sw];
#pragma unroll
      for (int mi = 0; mi < 2; ++mi)
#pragma unroll
        for (int ni = 0; ni < 8; ++ni)
          sacc[mi][ni] = MFMA16x16x32(qf[mi][ks], kf[ni], sacc[mi][ni], 0, 0, 0);
    }
    __syncthreads();  // all kf reads done; KP becomes Ps [128][136]

    // online softmax: lane holds rows mi*16+quad*4+j, cols ni*16+l15
#pragma unroll
    for (int mi = 0; mi < 2; ++mi) {
#pragma unroll
      for (int j = 0; j < 4; ++j) {
        const int rl = mi * 16 + quad * 4 + j;
        const int rowg = q0 + rl;
        float t0[8];
#pragma unroll
        for (int ni = 0; ni < 8; ++ni) {
          const int kg = kb_ + ni * 16 + l15;
          const float s = sacc[mi][ni][j] * cs;
          t0[ni] = (kg <= rowg) ? s : -1e30f;
        }
        float rm = fmaxf(fmaxf(fmaxf(t0[0], t0[1]), fmaxf(t0[2], t0[3])),
                         fmaxf(fmaxf(t0[4], t0[5]), fmaxf(t0[6], t0[7])));
        rm = fmaxf(rm, __shfl_xor(rm, 1));
        rm = fmaxf(rm, __shfl_xor(rm, 2));
        rm = fmaxf(rm, __shfl_xor(rm, 4));
        rm = fmaxf(rm, __shfl_xor(rm, 8));
        const float mold = mrun[mi][j];
        const float mnew = fmaxf(mold, rm);
        const float alpha = __builtin_amdgcn_exp2f(mold - mnew);
        float rs = 0.f;
#pragma unroll
        for (int ni = 0; ni < 8; ++ni) {
          const float pe = __builtin_amdgcn_exp2f(t0[ni] - mnew);
          rs += pe;
          KP[(w * 32 + rl) * 136 + ni * 16 + l15] = f2bf(pe);  // Ps
        }
        rs += __shfl_xor(rs, 1);
        rs += __shfl_xor(rs, 2);
        rs += __shfl_xor(rs, 4);
        rs += __shfl_xor(rs, 8);
        lrun[mi][j] = lrun[mi][j] * alpha + rs;
        mrun[mi][j] = mnew;
#pragma unroll
        for (int oi = 0; oi < 8; ++oi) oacc[mi][oi][j] *= alpha;
      }
    }

    // O += P V  (Ps rows wave-private -> no barrier; Vs valid till next stage)
#pragma unroll
    for (int ks = 0; ks < 4; ++ks) {
      const int sw = ((ks * 4 + quad) ^ x7) * 8;
      short8 pf[2], vf[8];
#pragma unroll
      for (int mi = 0; mi < 2; ++mi)
        pf[mi] = *(const short8*)&KP[(w * 32 + mi * 16 + l15) * 136 +
                                     ks * 32 + quad * 8];
#pragma unroll
      for (int oi = 0; oi < 8; ++oi)
        vf[oi] = *(const short8*)&Vs[(oi * 16 + l15) * 128 + sw];
#pragma unroll
      for (int mi = 0; mi < 2; ++mi)
#pragma unroll
        for (int oi = 0; oi < 8; ++oi)
          oacc[mi][oi] = MFMA16x16x32(pf[mi], vf[oi], oacc[mi][oi], 0, 0, 0);
    }
  }

  // epilogue: O /= l, write merged-heads bf16 [B,S,D]
#pragma unroll
  for (int mi = 0; mi < 2; ++mi) {
    float inv[4];
#pragma unroll
    for (int j = 0; j < 4; ++j) inv[j] = 1.f / lrun[mi][j];
#pragma unroll
    for (int oi = 0; oi < 8; ++oi) {
      const int oc = oi * 16 + l15;
#pragma unroll
      for (int j = 0; j < 4; ++j) {
        const int s = q0 + mi * 16 + quad * 4 + j;
        O[((size_t)(b * S_LEN + s)) * DMODEL + h * 128 + oc] =
            f2bf(oacc[mi][oi][j] * inv[j]);
      }
    }
  }
}

// ---------------------------------------------------------------------------
extern "C" void kernel_launch(void* const* d_in, const int* in_sizes, int n_in,
                              void* d_out, int out_size, void* d_ws,
                              size_t ws_size, hipStream_t stream) {
  const float* x  = (const float*)d_in[0];
  const float* Wq = (const float*)d_in[1];
  const float* bq = (const float*)d_in[2];
  const float* Wk = (const float*)d_in[3];
  const float* bk = (const float*)d_in[4];
  const float* Wv = (const float*)d_in[5];
  const float* bv = (const float*)d_in[6];
  const float* Wd = (const float*)d_in[7];
  const float* bd = (const float*)d_in[8];

  float* out   = (float*)d_out;
  float* a_out = out;                     // [B,S,D] fp32 (written last)
  float* k_out = out + A_ELEMS;           // present[0] fp32 [B,H,S,hd]
  float* v_out = out + 2 * A_ELEMS;       // present[1] fp32 [B,H,S,hd]
  ushort_t* ob  = (ushort_t*)d_out;
  ushort_t* xb   = ob;                    // bf16 x, a-region bytes [0,16.78M)
  ushort_t* q_ws = ob + A_ELEMS;          // bf16 q, a-region bytes [16.78M,33.55M)

  ushort_t* ws  = (ushort_t*)d_ws;        // 83.9 MB used
  ushort_t* wtq = ws;
  ushort_t* wtk = ws + W_ELEMS;
  ushort_t* wtv = ws + 2 * (size_t)W_ELEMS;
  ushort_t* wtd = ws + 3 * (size_t)W_ELEMS;
  ushort_t* attn_ws = ws + 4 * (size_t)W_ELEMS;            // bf16 [B,S,D]
  ushort_t* kb_ws   = attn_ws + (size_t)A_ELEMS;           // bf16 [B,H,S,hd]
  ushort_t* vt_ws   = attn_ws + 2 * (size_t)A_ELEMS;       // bf16 [B,H,hd,S]

  conv_x<<<4096, 256, 0, stream>>>(x, xb);
  trans_w<<<dim3(32, 32, 4), 256, 0, stream>>>(Wq, Wk, Wv, Wd,
                                               wtq, wtk, wtv, wtd);
  gemm_qkv<<<768, 512, 0, stream>>>(xb, wtq, wtk, wtv, bq, bk, bv,
                                    q_ws, k_out, v_out, kb_ws);
  trans_v<<<dim3(32, 2, 32), 256, 0, stream>>>(v_out, vt_ws);
  attn_fwd<<<512, 256, 0, stream>>>(q_ws, kb_ws, vt_ws, attn_ws);
  gemm_proj<<<256, 512, 0, stream>>>(attn_ws, wtd, bd, a_out);
}

// Round 8
// 446.624 us; speedup vs baseline: 1.1372x; 1.1372x over previous
//
#include <hip/hip_runtime.h>

// Attention_25855703122265: B=2, S=2048, D=2048, H=16, hd=128, causal prefill.
// fp32 I/O; bf16 MFMA compute.
//
// Round 13: revert to round-4 known-good (446.6us) + two isolated softmax
// cuts in attn_fwd v3 (v4's 512-block grid REGRESSED: scheduler does not
// co-place paired blocks -> imbalance; reverted to in-block seg pairing):
//  - mask skip: kt<qt tiles have no masked keys (block-uniform branch).
//  - T13 defer-rescale: if __all(rm <= mold+8) keep m_old; skip alpha
//    exp2 + lrun scale + 32 oacc muls. P bounded by 2^8; 1/l normalizes.
//  - GEMMs: round-8 2-phase core (measured 141.9us qkv), unchanged.
//
// Memory map:
//  d_out (fp32): a [0,8.39M) | k present [8.39M,16.78M) | v [16.78M,25.17M)
//    a-region reused as scratch until proj: xb bf16 @ bytes [0,16.78M),
//    q bf16 @ bytes [16.78M,33.55M)  (dead before proj GEMM writes a).
//  d_ws (83.9 MB): wt_q|wt_k|wt_v|wt_d (bf16 [N,K], 8.39MB each)
//    | attn_ws bf16 16.78MB | kb_ws bf16 16.78MB | vt_ws bf16 16.78MB

typedef unsigned short ushort_t;
typedef __attribute__((ext_vector_type(8))) short short8;   // 8 x bf16
typedef __attribute__((ext_vector_type(4))) float f32x4;

#define MFMA16x16x32 __builtin_amdgcn_mfma_f32_16x16x32_bf16
#define S_LEN   2048
#define DMODEL  2048
#define A_ELEMS 8388608   // B*S*D
#define W_ELEMS 4194304   // D*D

__device__ __forceinline__ ushort_t f2bf(float x) {
  unsigned u = __float_as_uint(x);
  u += 0x7FFFu + ((u >> 16) & 1u);
  return (ushort_t)(u >> 16);
}
__device__ __forceinline__ unsigned pack2(float lo, float hi) {
  return (unsigned)f2bf(lo) | ((unsigned)f2bf(hi) << 16);
}
struct f8 { float v[8]; };
__device__ __forceinline__ f8 ld8f(const float* p) {
  f8 r;
  float4 a = *(const float4*)p, b = *(const float4*)(p + 4);
  r.v[0]=a.x; r.v[1]=a.y; r.v[2]=a.z; r.v[3]=a.w;
  r.v[4]=b.x; r.v[5]=b.y; r.v[6]=b.z; r.v[7]=b.w;
  return r;
}
__device__ __forceinline__ uint4 cvt8(const f8& f) {
  uint4 o;
  o.x = pack2(f.v[0], f.v[1]); o.y = pack2(f.v[2], f.v[3]);
  o.z = pack2(f.v[4], f.v[5]); o.w = pack2(f.v[6], f.v[7]);
  return o;
}

// async global->LDS, 16B/lane; dest = wave-uniform base + lane*16
typedef const __attribute__((address_space(1))) void* gas_t;
typedef __attribute__((address_space(3))) void* las_t;
__device__ __forceinline__ void gld16(const void* g, void* l) {
  __builtin_amdgcn_global_load_lds((gas_t)(unsigned long long)g,
                                   (las_t)(unsigned)(unsigned long long)l,
                                   16, 0, 0);
}

// ---------------------------------------------------------------------------
// Prepass 1: x fp32 -> xb bf16 (straight convert, 8 elems/thread)
// ---------------------------------------------------------------------------
__global__ void __launch_bounds__(256) conv_x(const float* __restrict__ x,
                                              ushort_t* __restrict__ xb) {
  const int i = (blockIdx.x * 256 + threadIdx.x) * 8;
  f8 v = ld8f(x + i);
  *(uint4*)&xb[i] = cvt8(v);
}

// ---------------------------------------------------------------------------
// Prepass 2: W fp32 [K,N] -> wt bf16 [N,K]; 64x64 tiles; z picks weight
// ---------------------------------------------------------------------------
__global__ void __launch_bounds__(256) trans_w(
    const float* __restrict__ w0, const float* __restrict__ w1,
    const float* __restrict__ w2, const float* __restrict__ w3,
    ushort_t* __restrict__ o0, ushort_t* __restrict__ o1,
    ushort_t* __restrict__ o2, ushort_t* __restrict__ o3) {
  __shared__ float t[64][65];
  const float* src; ushort_t* dst;
  switch (blockIdx.z) {
    case 0: src = w0; dst = o0; break;
    case 1: src = w1; dst = o1; break;
    case 2: src = w2; dst = o2; break;
    default: src = w3; dst = o3; break;
  }
  const int kb = blockIdx.y * 64, nb = blockIdx.x * 64;
  const int r = threadIdx.x >> 3, c8 = (threadIdx.x & 7) * 8;
#pragma unroll
  for (int i = 0; i < 64; i += 32) {
    *(float4*)&t[r + i][c8]     = *(const float4*)&src[(size_t)(kb + r + i) * DMODEL + nb + c8];
    *(float4*)&t[r + i][c8 + 4] = *(const float4*)&src[(size_t)(kb + r + i) * DMODEL + nb + c8 + 4];
  }
  __syncthreads();
#pragma unroll
  for (int i = 0; i < 64; i += 32) {
    float tmp[8];
#pragma unroll
    for (int j = 0; j < 8; ++j) tmp[j] = t[c8 + j][r + i];
    uint4 o;
    o.x = pack2(tmp[0], tmp[1]); o.y = pack2(tmp[2], tmp[3]);
    o.z = pack2(tmp[4], tmp[5]); o.w = pack2(tmp[6], tmp[7]);
    *(uint4*)&dst[(size_t)(nb + r + i) * DMODEL + kb + c8] = o;
  }
}

// ---------------------------------------------------------------------------
// Prepass 3 (after gemm_qkv): v fp32 [B,H,S,128] -> vt bf16 [B,H,128,S]
// ---------------------------------------------------------------------------
__global__ void __launch_bounds__(256) trans_v(const float* __restrict__ v,
                                               ushort_t* __restrict__ vt) {
  __shared__ float t[64][65];
  const int bh = blockIdx.z;
  const int sb = blockIdx.x * 64, db = blockIdx.y * 64;
  const float* src = v + (size_t)bh * S_LEN * 128;
  ushort_t* dst = vt + (size_t)bh * 128 * S_LEN;
  const int r = threadIdx.x >> 3, c8 = (threadIdx.x & 7) * 8;
#pragma unroll
  for (int i = 0; i < 64; i += 32) {
    *(float4*)&t[r + i][c8]     = *(const float4*)&src[(size_t)(sb + r + i) * 128 + db + c8];
    *(float4*)&t[r + i][c8 + 4] = *(const float4*)&src[(size_t)(sb + r + i) * 128 + db + c8 + 4];
  }
  __syncthreads();
#pragma unroll
  for (int i = 0; i < 64; i += 32) {
    float tmp[8];
#pragma unroll
    for (int j = 0; j < 8; ++j) tmp[j] = t[c8 + j][r + i];
    uint4 o;
    o.x = pack2(tmp[0], tmp[1]); o.y = pack2(tmp[2], tmp[3]);
    o.z = pack2(tmp[4], tmp[5]); o.w = pack2(tmp[6], tmp[7]);
    *(uint4*)&dst[(size_t)(db + r + i) * S_LEN + sb + c8] = o;
  }
}

// ---------------------------------------------------------------------------
// 2-phase GEMM core (round-8, measured 141.9us qkv): C[128,256] tile, BK=64,
// 8 waves (2Mx4N, 64x64 per wave). LDS: A [2][2][128][32] (32KB) +
// B [2][2][256][32] (64KB) = 96KB. Slot-XOR swizzle both sides (0 conflicts).
// Per K-tile: 6 gld16 (tile start) + 2x{8 ds_read_b128 + 16 MFMA setprio}
// + one __syncthreads.  nt = 2048/64 = 32.
// ---------------------------------------------------------------------------
#define ABUF (2 * 128 * 32)   // elems per A double-buffer slot (16KB)
#define BBUF (2 * 256 * 32)   // elems per B double-buffer slot (32KB)

__device__ __forceinline__ void stage6(
    const ushort_t* __restrict__ gA, const ushort_t* __restrict__ gB,
    ushort_t* An, ushort_t* Bn, int t, int w, size_t soff) {
  const size_t kc = (size_t)t * 64;
#pragma unroll
  for (int i = 0; i < 2; ++i) {
    const int c = 2 * w + i, kh = c >> 3, rg = c & 7;
    gld16(gA + (size_t)(rg * 16) * 2048 + kc + kh * 32 + soff,
          An + (kh * 128 + rg * 16) * 32);
  }
#pragma unroll
  for (int i = 0; i < 4; ++i) {
    const int c = 4 * w + i, kh = c >> 4, rg = c & 15;
    gld16(gB + (size_t)(rg * 16) * 2048 + kc + kh * 32 + soff,
          Bn + (kh * 256 + rg * 16) * 32);
  }
}

__device__ __forceinline__ void gemm2p_core(
    const ushort_t* __restrict__ gA, const ushort_t* __restrict__ gB,
    ushort_t* AsF, ushort_t* BsF, int w, int lane, f32x4 acc[4][4]) {
  const int l15 = lane & 15, quad = lane >> 4;
  const int wm = w >> 2, wn = w & 3;
  const size_t soff = (size_t)(lane >> 2) * 2048 +
                      (((lane & 3) ^ ((lane >> 3) & 3)) * 8);
  const int rslot8 = (quad ^ ((l15 >> 1) & 3)) * 8;
  const int arow = wm * 64 + l15;
  const int brow = wn * 64 + l15;

  stage6(gA, gB, AsF, BsF, 0, w, soff);
  __syncthreads();

  for (int t = 0; t < 32; ++t) {
    ushort_t* Ab = AsF + (t & 1) * ABUF;
    ushort_t* Bb = BsF + (t & 1) * BBUF;
    if (t + 1 < 32)
      stage6(gA, gB, AsF + ((t + 1) & 1) * ABUF, BsF + ((t + 1) & 1) * BBUF,
             t + 1, w, soff);
#pragma unroll
    for (int kh = 0; kh < 2; ++kh) {
      short8 af[4], bf[4];
#pragma unroll
      for (int mi = 0; mi < 4; ++mi)
        af[mi] = *(const short8*)&Ab[(kh * 128 + arow + mi * 16) * 32 + rslot8];
#pragma unroll
      for (int ni = 0; ni < 4; ++ni)
        bf[ni] = *(const short8*)&Bb[(kh * 256 + brow + ni * 16) * 32 + rslot8];
      __builtin_amdgcn_s_setprio(1);
#pragma unroll
      for (int mi = 0; mi < 4; ++mi)
#pragma unroll
        for (int ni = 0; ni < 4; ++ni)
          acc[mi][ni] = MFMA16x16x32(af[mi], bf[ni], acc[mi][ni], 0, 0, 0);
      __builtin_amdgcn_s_setprio(0);
    }
    __syncthreads();
  }
}

// ---------------------------------------------------------------------------
// Fused QKV GEMM (2-phase core). 768 blocks = 3 exact CU rounds.
// XCD swizzle: logical = (bx&7)*96 + (bx>>3).
// ---------------------------------------------------------------------------
__global__ void __launch_bounds__(512, 2) gemm_qkv(
    const ushort_t* __restrict__ xb,
    const ushort_t* __restrict__ wtq, const ushort_t* __restrict__ wtk,
    const ushort_t* __restrict__ wtv,
    const float* __restrict__ bq, const float* __restrict__ bk,
    const float* __restrict__ bv,
    ushort_t* __restrict__ qout, float* __restrict__ kout,
    float* __restrict__ vout, ushort_t* __restrict__ kb16) {
  __shared__ ushort_t As_[2 * ABUF];   // 32KB
  __shared__ ushort_t Bs_[2 * BBUF];   // 64KB
  const int tid = threadIdx.x, w = tid >> 6, lane = tid & 63;
  const int l15 = lane & 15, quad = lane >> 4;
  const int wm = w >> 2, wn = w & 3;
  const int bx = blockIdx.x;
  const int logical = (bx & 7) * 96 + (bx >> 3);
  const int wid = logical >> 8, idx = logical & 255;
  const int tn = idx & 7, tm = idx >> 3;
  const ushort_t* Wt = wid == 0 ? wtq : (wid == 1 ? wtk : wtv);
  const float* bias = wid == 0 ? bq : (wid == 1 ? bk : bv);

  f32x4 acc[4][4] = {};
  gemm2p_core(xb + (size_t)(tm * 128) * 2048, Wt + (size_t)(tn * 256) * 2048,
              As_, Bs_, w, lane, acc);

  const int row0 = tm * 128 + wm * 64, col0 = tn * 256 + wn * 64;
#pragma unroll
  for (int ni = 0; ni < 4; ++ni) {
    const int col = col0 + ni * 16 + l15;
    const float bv_ = bias[col];
    const int h = col >> 7, d = col & 127;
#pragma unroll
    for (int mi = 0; mi < 4; ++mi) {
#pragma unroll
      for (int j = 0; j < 4; ++j) {
        const int row = row0 + mi * 16 + quad * 4 + j;
        const int b = row >> 11, s = row & 2047;
        const size_t idxg = (size_t)(((b * 16 + h) * 2048 + s)) * 128 + d;
        const float v = acc[mi][ni][j] + bv_;
        if (wid == 0) qout[idxg] = f2bf(v);
        else if (wid == 1) { kout[idxg] = v; kb16[idxg] = f2bf(v); }
        else vout[idxg] = v;
      }
    }
  }
}

// ---------------------------------------------------------------------------
// Proj GEMM (2-phase core): a[4096,2048] fp32 = attn_ws bf16 @ wt_d^T + bd
// 256 blocks = 1 exact CU round; logical = (bx&7)*32 + (bx>>3).
// ---------------------------------------------------------------------------
__global__ void __launch_bounds__(512, 2) gemm_proj(
    const ushort_t* __restrict__ A, const ushort_t* __restrict__ Wt,
    const float* __restrict__ bias, float* __restrict__ C) {
  __shared__ ushort_t As_[2 * ABUF];
  __shared__ ushort_t Bs_[2 * BBUF];
  const int tid = threadIdx.x, w = tid >> 6, lane = tid & 63;
  const int l15 = lane & 15, quad = lane >> 4;
  const int wm = w >> 2, wn = w & 3;
  const int logical = (blockIdx.x & 7) * 32 + (blockIdx.x >> 3);
  const int tn = logical & 7, tm = logical >> 3;

  f32x4 acc[4][4] = {};
  gemm2p_core(A + (size_t)(tm * 128) * 2048, Wt + (size_t)(tn * 256) * 2048,
              As_, Bs_, w, lane, acc);

  const int row0 = tm * 128 + wm * 64, col0 = tn * 256 + wn * 64;
#pragma unroll
  for (int ni = 0; ni < 4; ++ni) {
    const int col = col0 + ni * 16 + l15;
    const float bv_ = bias[col];
#pragma unroll
    for (int mi = 0; mi < 4; ++mi)
#pragma unroll
      for (int j = 0; j < 4; ++j) {
        const int row = row0 + mi * 16 + quad * 4 + j;
        C[(size_t)row * DMODEL + col] = acc[mi][ni][j] + bv_;
      }
  }
}

// ---------------------------------------------------------------------------
// Flash causal attention v3.1. 256 blocks x 512 thr (8 waves x 16 q-rows),
// in-block seg pairing {15-pr, pr} -> deterministic 17 iters, 1 block/CU.
// v3 + (a) block-uniform mask skip for kt<qt, (b) T13 defer-rescale THR=8.
// ---------------------------------------------------------------------------
__global__ void __launch_bounds__(512, 2) attn_fwd(
    const ushort_t* __restrict__ Q, const ushort_t* __restrict__ Kb,
    const ushort_t* __restrict__ Vt, ushort_t* __restrict__ O) {
  __shared__ ushort_t KP[128 * 136];  // K tile [key][d] (linear 128x128) / Ps
  __shared__ ushort_t Vs[128 * 128];  // V^T tile [d][key] (linear, swizzled)
  const int tid = threadIdx.x;
  const int w = tid >> 6, lane = tid & 63;
  const int l15 = lane & 15, quad = lane >> 4;
  const int x7 = l15 & 7;                   // read-side swizzle term
  const int bh = blockIdx.x & 31, pr = blockIdx.x >> 5;
  const int b = bh >> 4, h = bh & 15;
  const size_t base  = (size_t)bh * (S_LEN * 128);  // Q,Kb: [bh][s][128]
  const size_t vbase = (size_t)bh * (128 * S_LEN);  // Vt:   [bh][d][s]
  const float cs = 0.08838834764831845f * 1.4426950408889634f;  // 1/sqrt(128)*log2(e)

  const int srow = lane >> 4;     // staging: row within 4-row group
  const int schunk = lane & 15;   // staging: 16B slot within 256B row

  for (int seg = 0; seg < 2; ++seg) {
    const int qt = (seg == 0) ? (15 - pr) : pr;
    const int q0 = qt * 128 + w * 16;   // this wave's first q row

    // Q fragments: A-layout A[m=l15][k=quad*8+j]
    short8 qf[4];
#pragma unroll
    for (int ks = 0; ks < 4; ++ks)
      qf[ks] = *(const short8*)&Q[base + (size_t)(q0 + l15) * 128 + ks * 32 + quad * 8];

    f32x4 oacc[8] = {};
    float mrun[4], lrun[4];
#pragma unroll
    for (int j = 0; j < 4; ++j) { mrun[j] = -1e30f; lrun[j] = 0.f; }

    for (int kt = 0; kt <= qt; ++kt) {
      const int kb_ = kt * 128;
      __syncthreads();  // prev iter's Ps/Vs reads done; buffers free
#pragma unroll
      for (int i = 0; i < 4; ++i) {
        const int r = w * 16 + i * 4 + srow;
        const int c = schunk ^ (r & 7);           // pre-swizzled source chunk
        gld16(Kb + base + (size_t)(kb_ + r) * 128 + c * 8,
              (void*)(KP + (w * 16 + i * 4) * 128));
        gld16(Vt + vbase + (size_t)r * S_LEN + kb_ + c * 8,
              (void*)(Vs + (w * 16 + i * 4) * 128));
      }
      __syncthreads();  // drains vmcnt; staged data ready

      // S = Q K^T over 128 keys
      f32x4 sacc[8] = {};
#pragma unroll
      for (int ks = 0; ks < 4; ++ks) {
        const int sw = ((ks * 4 + quad) ^ x7) * 8;  // swizzled chunk offset
        short8 kf[8];
#pragma unroll
        for (int ni = 0; ni < 8; ++ni)
          kf[ni] = *(const short8*)&KP[(ni * 16 + l15) * 128 + sw];
#pragma unroll
        for (int ni = 0; ni < 8; ++ni)
          sacc[ni] = MFMA16x16x32(qf[ks], kf[ni], sacc[ni], 0, 0, 0);
      }
      __syncthreads();  // all kf reads done; KP becomes Ps [128][136]

      // online softmax: lane holds rows quad*4+j, cols ni*16+l15
      const bool diag = (kt == qt);   // block-uniform: only diag tile masks
#pragma unroll
      for (int j = 0; j < 4; ++j) {
        const int rl = quad * 4 + j;
        const int rowg = q0 + rl;
        float t0[8];
        if (diag) {
#pragma unroll
          for (int ni = 0; ni < 8; ++ni) {
            const int kg = kb_ + ni * 16 + l15;
            const float s = sacc[ni][j] * cs;
            t0[ni] = (kg <= rowg) ? s : -1e30f;
          }
        } else {
#pragma unroll
          for (int ni = 0; ni < 8; ++ni) t0[ni] = sacc[ni][j] * cs;
        }
        float rm = fmaxf(fmaxf(fmaxf(t0[0], t0[1]), fmaxf(t0[2], t0[3])),
                         fmaxf(fmaxf(t0[4], t0[5]), fmaxf(t0[6], t0[7])));
        rm = fmaxf(rm, __shfl_xor(rm, 1));
        rm = fmaxf(rm, __shfl_xor(rm, 2));
        rm = fmaxf(rm, __shfl_xor(rm, 4));
        rm = fmaxf(rm, __shfl_xor(rm, 8));
        // T13 defer-rescale: only rescale when some row grew by > 8 (log2)
        if (!__all(rm <= mrun[j] + 8.0f)) {
          const float mold = mrun[j];
          const float mnew = fmaxf(mold, rm);
          const float alpha = __builtin_amdgcn_exp2f(mold - mnew);
          lrun[j] *= alpha;
          mrun[j] = mnew;
#pragma unroll
          for (int oi = 0; oi < 8; ++oi) oacc[oi][j] *= alpha;
        }
        const float mref = mrun[j];
        float rs = 0.f;
#pragma unroll
        for (int ni = 0; ni < 8; ++ni) {
          const float pe = __builtin_amdgcn_exp2f(t0[ni] - mref);
          rs += pe;
          KP[(w * 16 + rl) * 136 + ni * 16 + l15] = f2bf(pe);  // Ps
        }
        rs += __shfl_xor(rs, 1);
        rs += __shfl_xor(rs, 2);
        rs += __shfl_xor(rs, 4);
        rs += __shfl_xor(rs, 8);
        lrun[j] += rs;
      }

      // O += P V  (Ps rows wave-private -> no barrier; Vs valid till next stage)
#pragma unroll
      for (int ks = 0; ks < 4; ++ks) {
        const int sw = ((ks * 4 + quad) ^ x7) * 8;
        short8 pf = *(const short8*)&KP[(w * 16 + l15) * 136 + ks * 32 + quad * 8];
        short8 vf[8];
#pragma unroll
        for (int oi = 0; oi < 8; ++oi)
          vf[oi] = *(const short8*)&Vs[(oi * 16 + l15) * 128 + sw];
#pragma unroll
        for (int oi = 0; oi < 8; ++oi)
          oacc[oi] = MFMA16x16x32(pf, vf[oi], oacc[oi], 0, 0, 0);
      }
    }

    // epilogue: O /= l, write merged-heads bf16 [B,S,D]
    {
      float inv[4];
#pragma unroll
      for (int j = 0; j < 4; ++j) inv[j] = 1.f / lrun[j];
#pragma unroll
      for (int oi = 0; oi < 8; ++oi) {
        const int oc = oi * 16 + l15;
#pragma unroll
        for (int j = 0; j < 4; ++j) {
          const int s = q0 + quad * 4 + j;
          O[((size_t)(b * S_LEN + s)) * DMODEL + h * 128 + oc] =
              f2bf(oacc[oi][j] * inv[j]);
        }
      }
    }
  }
}

// ---------------------------------------------------------------------------
extern "C" void kernel_launch(void* const* d_in, const int* in_sizes, int n_in,
                              void* d_out, int out_size, void* d_ws,
                              size_t ws_size, hipStream_t stream) {
  const float* x  = (const float*)d_in[0];
  const float* Wq = (const float*)d_in[1];
  const float* bq = (const float*)d_in[2];
  const float* Wk = (const float*)d_in[3];
  const float* bk = (const float*)d_in[4];
  const float* Wv = (const float*)d_in[5];
  const float* bv = (const float*)d_in[6];
  const float* Wd = (const float*)d_in[7];
  const float* bd = (const float*)d_in[8];

  float* out   = (float*)d_out;
  float* a_out = out;                     // [B,S,D] fp32 (written last)
  float* k_out = out + A_ELEMS;           // present[0] fp32 [B,H,S,hd]
  float* v_out = out + 2 * A_ELEMS;       // present[1] fp32 [B,H,S,hd]
  ushort_t* ob  = (ushort_t*)d_out;
  ushort_t* xb   = ob;                    // bf16 x, a-region bytes [0,16.78M)
  ushort_t* q_ws = ob + A_ELEMS;          // bf16 q, a-region bytes [16.78M,33.55M)

  ushort_t* ws  = (ushort_t*)d_ws;        // 83.9 MB used
  ushort_t* wtq = ws;
  ushort_t* wtk = ws + W_ELEMS;
  ushort_t* wtv = ws + 2 * (size_t)W_ELEMS;
  ushort_t* wtd = ws + 3 * (size_t)W_ELEMS;
  ushort_t* attn_ws = ws + 4 * (size_t)W_ELEMS;            // bf16 [B,S,D]
  ushort_t* kb_ws   = attn_ws + (size_t)A_ELEMS;           // bf16 [B,H,S,hd]
  ushort_t* vt_ws   = attn_ws + 2 * (size_t)A_ELEMS;       // bf16 [B,H,hd,S]

  conv_x<<<4096, 256, 0, stream>>>(x, xb);
  trans_w<<<dim3(32, 32, 4), 256, 0, stream>>>(Wq, Wk, Wv, Wd,
                                               wtq, wtk, wtv, wtd);
  gemm_qkv<<<768, 512, 0, stream>>>(xb, wtq, wtk, wtv, bq, bk, bv,
                                    q_ws, k_out, v_out, kb_ws);
  trans_v<<<dim3(32, 2, 32), 256, 0, stream>>>(v_out, vt_ws);
  attn_fwd<<<256, 512, 0, stream>>>(q_ws, kb_ws, vt_ws, attn_ws);
  gemm_proj<<<256, 512, 0, stream>>>(attn_ws, wtd, bd, a_out);
}

// Round 9
// 440.136 us; speedup vs baseline: 1.1540x; 1.0147x over previous
//
#include <hip/hip_runtime.h>

// Attention_25855703122265: B=2, S=2048, D=2048, H=16, hd=128, causal prefill.
// fp32 I/O; bf16 MFMA compute.
//
// Round 14:
//  - attn_fwd v3.2: 512 blocks x 256 thr (4 waves x 16 q-rows). Block =
//    (bh, pr, rowhalf); seg-pair {15-pr, pr} kept -> EVERY block runs
//    exactly 17 K-iters (placement-independent balance, unlike v4).
//    66KB LDS -> 2 blocks/CU: cross-block overlap fills barrier stalls
//    (r13 showed VALU cuts save ~0 -> attn is latency/barrier-bound).
//  - trans_v ELIMINATED: gemm_qkv wid==2 epilogue transposes acc via LDS
//    (reuses dead Bs_) and writes vt bf16 coalesced. Bit-identical vt.
//  - GEMM cores unchanged (r8 2-phase, 141.9us qkv measured).
//
// Memory map:
//  d_out (fp32): a [0,8.39M) | k present [8.39M,16.78M) | v [16.78M,25.17M)
//    a-region reused as scratch until proj: xb bf16 @ bytes [0,16.78M),
//    q bf16 @ bytes [16.78M,33.55M)  (dead before proj GEMM writes a).
//  d_ws (83.9 MB): wt_q|wt_k|wt_v|wt_d (bf16 [N,K], 8.39MB each)
//    | attn_ws bf16 16.78MB | kb_ws bf16 16.78MB | vt_ws bf16 16.78MB

typedef unsigned short ushort_t;
typedef __attribute__((ext_vector_type(8))) short short8;   // 8 x bf16
typedef __attribute__((ext_vector_type(4))) float f32x4;

#define MFMA16x16x32 __builtin_amdgcn_mfma_f32_16x16x32_bf16
#define S_LEN   2048
#define DMODEL  2048
#define A_ELEMS 8388608   // B*S*D
#define W_ELEMS 4194304   // D*D

__device__ __forceinline__ ushort_t f2bf(float x) {
  unsigned u = __float_as_uint(x);
  u += 0x7FFFu + ((u >> 16) & 1u);
  return (ushort_t)(u >> 16);
}
__device__ __forceinline__ unsigned pack2(float lo, float hi) {
  return (unsigned)f2bf(lo) | ((unsigned)f2bf(hi) << 16);
}
struct f8 { float v[8]; };
__device__ __forceinline__ f8 ld8f(const float* p) {
  f8 r;
  float4 a = *(const float4*)p, b = *(const float4*)(p + 4);
  r.v[0]=a.x; r.v[1]=a.y; r.v[2]=a.z; r.v[3]=a.w;
  r.v[4]=b.x; r.v[5]=b.y; r.v[6]=b.z; r.v[7]=b.w;
  return r;
}
__device__ __forceinline__ uint4 cvt8(const f8& f) {
  uint4 o;
  o.x = pack2(f.v[0], f.v[1]); o.y = pack2(f.v[2], f.v[3]);
  o.z = pack2(f.v[4], f.v[5]); o.w = pack2(f.v[6], f.v[7]);
  return o;
}

// async global->LDS, 16B/lane; dest = wave-uniform base + lane*16
typedef const __attribute__((address_space(1))) void* gas_t;
typedef __attribute__((address_space(3))) void* las_t;
__device__ __forceinline__ void gld16(const void* g, void* l) {
  __builtin_amdgcn_global_load_lds((gas_t)(unsigned long long)g,
                                   (las_t)(unsigned)(unsigned long long)l,
                                   16, 0, 0);
}

// ---------------------------------------------------------------------------
// Prepass 1: x fp32 -> xb bf16 (straight convert, 8 elems/thread)
// ---------------------------------------------------------------------------
__global__ void __launch_bounds__(256) conv_x(const float* __restrict__ x,
                                              ushort_t* __restrict__ xb) {
  const int i = (blockIdx.x * 256 + threadIdx.x) * 8;
  f8 v = ld8f(x + i);
  *(uint4*)&xb[i] = cvt8(v);
}

// ---------------------------------------------------------------------------
// Prepass 2: W fp32 [K,N] -> wt bf16 [N,K]; 64x64 tiles; z picks weight
// ---------------------------------------------------------------------------
__global__ void __launch_bounds__(256) trans_w(
    const float* __restrict__ w0, const float* __restrict__ w1,
    const float* __restrict__ w2, const float* __restrict__ w3,
    ushort_t* __restrict__ o0, ushort_t* __restrict__ o1,
    ushort_t* __restrict__ o2, ushort_t* __restrict__ o3) {
  __shared__ float t[64][65];
  const float* src; ushort_t* dst;
  switch (blockIdx.z) {
    case 0: src = w0; dst = o0; break;
    case 1: src = w1; dst = o1; break;
    case 2: src = w2; dst = o2; break;
    default: src = w3; dst = o3; break;
  }
  const int kb = blockIdx.y * 64, nb = blockIdx.x * 64;
  const int r = threadIdx.x >> 3, c8 = (threadIdx.x & 7) * 8;
#pragma unroll
  for (int i = 0; i < 64; i += 32) {
    *(float4*)&t[r + i][c8]     = *(const float4*)&src[(size_t)(kb + r + i) * DMODEL + nb + c8];
    *(float4*)&t[r + i][c8 + 4] = *(const float4*)&src[(size_t)(kb + r + i) * DMODEL + nb + c8 + 4];
  }
  __syncthreads();
#pragma unroll
  for (int i = 0; i < 64; i += 32) {
    float tmp[8];
#pragma unroll
    for (int j = 0; j < 8; ++j) tmp[j] = t[c8 + j][r + i];
    uint4 o;
    o.x = pack2(tmp[0], tmp[1]); o.y = pack2(tmp[2], tmp[3]);
    o.z = pack2(tmp[4], tmp[5]); o.w = pack2(tmp[6], tmp[7]);
    *(uint4*)&dst[(size_t)(nb + r + i) * DMODEL + kb + c8] = o;
  }
}

// ---------------------------------------------------------------------------
// 2-phase GEMM core (round-8, measured 141.9us qkv): C[128,256] tile, BK=64,
// 8 waves (2Mx4N, 64x64 per wave). LDS: A [2][2][128][32] (32KB) +
// B [2][2][256][32] (64KB) = 96KB. Slot-XOR swizzle both sides (0 conflicts).
// Per K-tile: 6 gld16 (tile start) + 2x{8 ds_read_b128 + 16 MFMA setprio}
// + one __syncthreads.  nt = 2048/64 = 32.
// ---------------------------------------------------------------------------
#define ABUF (2 * 128 * 32)   // elems per A double-buffer slot (16KB)
#define BBUF (2 * 256 * 32)   // elems per B double-buffer slot (32KB)

__device__ __forceinline__ void stage6(
    const ushort_t* __restrict__ gA, const ushort_t* __restrict__ gB,
    ushort_t* An, ushort_t* Bn, int t, int w, size_t soff) {
  const size_t kc = (size_t)t * 64;
#pragma unroll
  for (int i = 0; i < 2; ++i) {
    const int c = 2 * w + i, kh = c >> 3, rg = c & 7;
    gld16(gA + (size_t)(rg * 16) * 2048 + kc + kh * 32 + soff,
          An + (kh * 128 + rg * 16) * 32);
  }
#pragma unroll
  for (int i = 0; i < 4; ++i) {
    const int c = 4 * w + i, kh = c >> 4, rg = c & 15;
    gld16(gB + (size_t)(rg * 16) * 2048 + kc + kh * 32 + soff,
          Bn + (kh * 256 + rg * 16) * 32);
  }
}

__device__ __forceinline__ void gemm2p_core(
    const ushort_t* __restrict__ gA, const ushort_t* __restrict__ gB,
    ushort_t* AsF, ushort_t* BsF, int w, int lane, f32x4 acc[4][4]) {
  const int l15 = lane & 15, quad = lane >> 4;
  const int wm = w >> 2, wn = w & 3;
  const size_t soff = (size_t)(lane >> 2) * 2048 +
                      (((lane & 3) ^ ((lane >> 3) & 3)) * 8);
  const int rslot8 = (quad ^ ((l15 >> 1) & 3)) * 8;
  const int arow = wm * 64 + l15;
  const int brow = wn * 64 + l15;

  stage6(gA, gB, AsF, BsF, 0, w, soff);
  __syncthreads();

  for (int t = 0; t < 32; ++t) {
    ushort_t* Ab = AsF + (t & 1) * ABUF;
    ushort_t* Bb = BsF + (t & 1) * BBUF;
    if (t + 1 < 32)
      stage6(gA, gB, AsF + ((t + 1) & 1) * ABUF, BsF + ((t + 1) & 1) * BBUF,
             t + 1, w, soff);
#pragma unroll
    for (int kh = 0; kh < 2; ++kh) {
      short8 af[4], bf[4];
#pragma unroll
      for (int mi = 0; mi < 4; ++mi)
        af[mi] = *(const short8*)&Ab[(kh * 128 + arow + mi * 16) * 32 + rslot8];
#pragma unroll
      for (int ni = 0; ni < 4; ++ni)
        bf[ni] = *(const short8*)&Bb[(kh * 256 + brow + ni * 16) * 32 + rslot8];
      __builtin_amdgcn_s_setprio(1);
#pragma unroll
      for (int mi = 0; mi < 4; ++mi)
#pragma unroll
        for (int ni = 0; ni < 4; ++ni)
          acc[mi][ni] = MFMA16x16x32(af[mi], bf[ni], acc[mi][ni], 0, 0, 0);
      __builtin_amdgcn_s_setprio(0);
    }
    __syncthreads();
  }
}

// ---------------------------------------------------------------------------
// Fused QKV GEMM (2-phase core). 768 blocks = 3 exact CU rounds.
// XCD swizzle: logical = (bx&7)*96 + (bx>>3).
// wid==2 epilogue also writes vt bf16 [B,H,128,S] via LDS transpose (Bs_
// reused; two head-half passes) -> replaces the trans_v kernel.
// ---------------------------------------------------------------------------
__global__ void __launch_bounds__(512, 2) gemm_qkv(
    const ushort_t* __restrict__ xb,
    const ushort_t* __restrict__ wtq, const ushort_t* __restrict__ wtk,
    const ushort_t* __restrict__ wtv,
    const float* __restrict__ bq, const float* __restrict__ bk,
    const float* __restrict__ bv,
    ushort_t* __restrict__ qout, float* __restrict__ kout,
    float* __restrict__ vout, ushort_t* __restrict__ kb16,
    ushort_t* __restrict__ vt16) {
  __shared__ ushort_t As_[2 * ABUF];   // 32KB
  __shared__ ushort_t Bs_[2 * BBUF];   // 64KB
  const int tid = threadIdx.x, w = tid >> 6, lane = tid & 63;
  const int l15 = lane & 15, quad = lane >> 4;
  const int wm = w >> 2, wn = w & 3;
  const int bx = blockIdx.x;
  const int logical = (bx & 7) * 96 + (bx >> 3);
  const int wid = logical >> 8, idx = logical & 255;
  const int tn = idx & 7, tm = idx >> 3;
  const ushort_t* Wt = wid == 0 ? wtq : (wid == 1 ? wtk : wtv);
  const float* bias = wid == 0 ? bq : (wid == 1 ? bk : bv);

  f32x4 acc[4][4] = {};
  gemm2p_core(xb + (size_t)(tm * 128) * 2048, Wt + (size_t)(tn * 256) * 2048,
              As_, Bs_, w, lane, acc);

  const int row0 = tm * 128 + wm * 64, col0 = tn * 256 + wn * 64;
#pragma unroll
  for (int ni = 0; ni < 4; ++ni) {
    const int col = col0 + ni * 16 + l15;
    const float bv_ = bias[col];
    const int h = col >> 7, d = col & 127;
#pragma unroll
    for (int mi = 0; mi < 4; ++mi) {
#pragma unroll
      for (int j = 0; j < 4; ++j) {
        const int row = row0 + mi * 16 + quad * 4 + j;
        const int b = row >> 11, s = row & 2047;
        const size_t idxg = (size_t)(((b * 16 + h) * 2048 + s)) * 128 + d;
        const float v = acc[mi][ni][j] + bv_;
        if (wid == 0) qout[idxg] = f2bf(v);
        else if (wid == 1) { kout[idxg] = v; kb16[idxg] = f2bf(v); }
        else vout[idxg] = v;
      }
    }
  }

  if (wid == 2) {
    // fused V^T: two passes (head-half hh). T = Bs_ as [128 d][136] ushort.
    ushort_t* T = Bs_;
    const int s0 = (tm & 15) * 128;
    const int bh0 = (tm >> 4) * 16 + tn * 2;   // b*16 + tn*2 (+hh)
    for (int hh = 0; hh < 2; ++hh) {
      __syncthreads();                 // core/prev-pass LDS reads done
      if ((wn >> 1) == hh) {
#pragma unroll
        for (int ni = 0; ni < 4; ++ni) {
          const int cl = (wn & 1) * 64 + ni * 16 + l15;   // d = col & 127
          const float bv_ = bias[col0 + ni * 16 + l15];
#pragma unroll
          for (int mi = 0; mi < 4; ++mi) {
            const int r4 = wm * 64 + mi * 16 + quad * 4;  // row-local, x4
            uint2 p;
            p.x = pack2(acc[mi][ni][0] + bv_, acc[mi][ni][1] + bv_);
            p.y = pack2(acc[mi][ni][2] + bv_, acc[mi][ni][3] + bv_);
            *(uint2*)&T[cl * 136 + r4] = p;
          }
        }
      }
      __syncthreads();
      // coalesced copy-out: 2048 16B chunks, 512 thr x 4
#pragma unroll
      for (int ii = 0; ii < 4; ++ii) {
        const int ch = ii * 512 + tid;
        const int d = ch >> 4, sc = ch & 15;
        const uint4 v4 = *(const uint4*)&T[d * 136 + sc * 8];
        *(uint4*)&vt16[((size_t)((bh0 + hh) * 128 + d)) * 2048 + s0 + sc * 8] = v4;
      }
    }
  }
}

// ---------------------------------------------------------------------------
// Proj GEMM (2-phase core): a[4096,2048] fp32 = attn_ws bf16 @ wt_d^T + bd
// 256 blocks = 1 exact CU round; logical = (bx&7)*32 + (bx>>3).
// ---------------------------------------------------------------------------
__global__ void __launch_bounds__(512, 2) gemm_proj(
    const ushort_t* __restrict__ A, const ushort_t* __restrict__ Wt,
    const float* __restrict__ bias, float* __restrict__ C) {
  __shared__ ushort_t As_[2 * ABUF];
  __shared__ ushort_t Bs_[2 * BBUF];
  const int tid = threadIdx.x, w = tid >> 6, lane = tid & 63;
  const int l15 = lane & 15, quad = lane >> 4;
  const int wm = w >> 2, wn = w & 3;
  const int logical = (blockIdx.x & 7) * 32 + (blockIdx.x >> 3);
  const int tn = logical & 7, tm = logical >> 3;

  f32x4 acc[4][4] = {};
  gemm2p_core(A + (size_t)(tm * 128) * 2048, Wt + (size_t)(tn * 256) * 2048,
              As_, Bs_, w, lane, acc);

  const int row0 = tm * 128 + wm * 64, col0 = tn * 256 + wn * 64;
#pragma unroll
  for (int ni = 0; ni < 4; ++ni) {
    const int col = col0 + ni * 16 + l15;
    const float bv_ = bias[col];
#pragma unroll
    for (int mi = 0; mi < 4; ++mi)
#pragma unroll
      for (int j = 0; j < 4; ++j) {
        const int row = row0 + mi * 16 + quad * 4 + j;
        C[(size_t)row * DMODEL + col] = acc[mi][ni][j] + bv_;
      }
  }
}

// ---------------------------------------------------------------------------
// Flash causal attention v3.2. 512 blocks x 256 thr (4 waves x 16 q-rows).
// Block bx: bh = bx&31; pq = bx>>5; pr = pq&7; rh = pq>>3 (64-row half).
// Seg-pair {15-pr, pr} -> EVERY block runs exactly 17 K-iters (balance is
// placement-independent). 66KB LDS -> 2 blocks/CU cross-block overlap.
// Softmax: block-uniform diag mask skip + T13 defer-rescale (THR=8).
// ---------------------------------------------------------------------------
__global__ void __launch_bounds__(256, 2) attn_fwd(
    const ushort_t* __restrict__ Q, const ushort_t* __restrict__ Kb,
    const ushort_t* __restrict__ Vt, ushort_t* __restrict__ O) {
  __shared__ ushort_t KP[128 * 136];  // K tile [key][d] (linear 128x128) / Ps
  __shared__ ushort_t Vs[128 * 128];  // V^T tile [d][key] (linear, swizzled)
  const int tid = threadIdx.x;
  const int w = tid >> 6, lane = tid & 63;        // w in [0,4)
  const int l15 = lane & 15, quad = lane >> 4;
  const int x7 = l15 & 7;                   // read-side swizzle term
  const int bh = blockIdx.x & 31, pq = blockIdx.x >> 5;
  const int pr = pq & 7, rh = pq >> 3;
  const int b = bh >> 4, h = bh & 15;
  const size_t base  = (size_t)bh * (S_LEN * 128);  // Q,Kb: [bh][s][128]
  const size_t vbase = (size_t)bh * (128 * S_LEN);  // Vt:   [bh][d][s]
  const float cs = 0.08838834764831845f * 1.4426950408889634f;  // 1/sqrt(128)*log2(e)

  const int srow = lane >> 4;     // staging: row within 4-row group
  const int schunk = lane & 15;   // staging: 16B slot within 256B row

  for (int seg = 0; seg < 2; ++seg) {
    const int qt = (seg == 0) ? (15 - pr) : pr;
    const int q0 = qt * 128 + rh * 64 + w * 16;   // this wave's first q row

    // Q fragments: A-layout A[m=l15][k=quad*8+j]
    short8 qf[4];
#pragma unroll
    for (int ks = 0; ks < 4; ++ks)
      qf[ks] = *(const short8*)&Q[base + (size_t)(q0 + l15) * 128 + ks * 32 + quad * 8];

    f32x4 oacc[8] = {};
    float mrun[4], lrun[4];
#pragma unroll
    for (int j = 0; j < 4; ++j) { mrun[j] = -1e30f; lrun[j] = 0.f; }

    for (int kt = 0; kt <= qt; ++kt) {
      const int kb_ = kt * 128;
      __syncthreads();  // prev iter's Ps/Vs reads done; buffers free
      // stage K (128x128) + V^T (128x128): 4 waves x 32 rows each
#pragma unroll
      for (int i = 0; i < 8; ++i) {
        const int r = w * 32 + i * 4 + srow;
        const int c = schunk ^ (r & 7);           // pre-swizzled source chunk
        gld16(Kb + base + (size_t)(kb_ + r) * 128 + c * 8,
              (void*)(KP + (w * 32 + i * 4) * 128));
        gld16(Vt + vbase + (size_t)r * S_LEN + kb_ + c * 8,
              (void*)(Vs + (w * 32 + i * 4) * 128));
      }
      __syncthreads();  // drains vmcnt; staged data ready

      // S = Q K^T over 128 keys
      f32x4 sacc[8] = {};
#pragma unroll
      for (int ks = 0; ks < 4; ++ks) {
        const int sw = ((ks * 4 + quad) ^ x7) * 8;  // swizzled chunk offset
        short8 kf[8];
#pragma unroll
        for (int ni = 0; ni < 8; ++ni)
          kf[ni] = *(const short8*)&KP[(ni * 16 + l15) * 128 + sw];
#pragma unroll
        for (int ni = 0; ni < 8; ++ni)
          sacc[ni] = MFMA16x16x32(qf[ks], kf[ni], sacc[ni], 0, 0, 0);
      }
      __syncthreads();  // all kf reads done; KP becomes Ps [64][136]

      // online softmax: lane holds rows quad*4+j, cols ni*16+l15
      const bool diag = (kt == qt);   // block-uniform: only diag tile masks
#pragma unroll
      for (int j = 0; j < 4; ++j) {
        const int rl = quad * 4 + j;
        const int rowg = q0 + rl;
        float t0[8];
        if (diag) {
#pragma unroll
          for (int ni = 0; ni < 8; ++ni) {
            const int kg = kb_ + ni * 16 + l15;
            const float s = sacc[ni][j] * cs;
            t0[ni] = (kg <= rowg) ? s : -1e30f;
          }
        } else {
#pragma unroll
          for (int ni = 0; ni < 8; ++ni) t0[ni] = sacc[ni][j] * cs;
        }
        float rm = fmaxf(fmaxf(fmaxf(t0[0], t0[1]), fmaxf(t0[2], t0[3])),
                         fmaxf(fmaxf(t0[4], t0[5]), fmaxf(t0[6], t0[7])));
        rm = fmaxf(rm, __shfl_xor(rm, 1));
        rm = fmaxf(rm, __shfl_xor(rm, 2));
        rm = fmaxf(rm, __shfl_xor(rm, 4));
        rm = fmaxf(rm, __shfl_xor(rm, 8));
        // T13 defer-rescale: only rescale when some row grew by > 8 (log2)
        if (!__all(rm <= mrun[j] + 8.0f)) {
          const float mold = mrun[j];
          const float mnew = fmaxf(mold, rm);
          const float alpha = __builtin_amdgcn_exp2f(mold - mnew);
          lrun[j] *= alpha;
          mrun[j] = mnew;
#pragma unroll
          for (int oi = 0; oi < 8; ++oi) oacc[oi][j] *= alpha;
        }
        const float mref = mrun[j];
        float rs = 0.f;
#pragma unroll
        for (int ni = 0; ni < 8; ++ni) {
          const float pe = __builtin_amdgcn_exp2f(t0[ni] - mref);
          rs += pe;
          KP[(w * 16 + rl) * 136 + ni * 16 + l15] = f2bf(pe);  // Ps
        }
        rs += __shfl_xor(rs, 1);
        rs += __shfl_xor(rs, 2);
        rs += __shfl_xor(rs, 4);
        rs += __shfl_xor(rs, 8);
        lrun[j] += rs;
      }

      // O += P V  (Ps rows wave-private -> no barrier; Vs valid till next stage)
#pragma unroll
      for (int ks = 0; ks < 4; ++ks) {
        const int sw = ((ks * 4 + quad) ^ x7) * 8;
        short8 pf = *(const short8*)&KP[(w * 16 + l15) * 136 + ks * 32 + quad * 8];
        short8 vf[8];
#pragma unroll
        for (int oi = 0; oi < 8; ++oi)
          vf[oi] = *(const short8*)&Vs[(oi * 16 + l15) * 128 + sw];
#pragma unroll
        for (int oi = 0; oi < 8; ++oi)
          oacc[oi] = MFMA16x16x32(pf, vf[oi], oacc[oi], 0, 0, 0);
      }
    }

    // epilogue: O /= l, write merged-heads bf16 [B,S,D]
    {
      float inv[4];
#pragma unroll
      for (int j = 0; j < 4; ++j) inv[j] = 1.f / lrun[j];
#pragma unroll
      for (int oi = 0; oi < 8; ++oi) {
        const int oc = oi * 16 + l15;
#pragma unroll
        for (int j = 0; j < 4; ++j) {
          const int s = q0 + quad * 4 + j;
          O[((size_t)(b * S_LEN + s)) * DMODEL + h * 128 + oc] =
              f2bf(oacc[oi][j] * inv[j]);
        }
      }
    }
  }
}

// ---------------------------------------------------------------------------
extern "C" void kernel_launch(void* const* d_in, const int* in_sizes, int n_in,
                              void* d_out, int out_size, void* d_ws,
                              size_t ws_size, hipStream_t stream) {
  const float* x  = (const float*)d_in[0];
  const float* Wq = (const float*)d_in[1];
  const float* bq = (const float*)d_in[2];
  const float* Wk = (const float*)d_in[3];
  const float* bk = (const float*)d_in[4];
  const float* Wv = (const float*)d_in[5];
  const float* bv = (const float*)d_in[6];
  const float* Wd = (const float*)d_in[7];
  const float* bd = (const float*)d_in[8];

  float* out   = (float*)d_out;
  float* a_out = out;                     // [B,S,D] fp32 (written last)
  float* k_out = out + A_ELEMS;           // present[0] fp32 [B,H,S,hd]
  float* v_out = out + 2 * A_ELEMS;       // present[1] fp32 [B,H,S,hd]
  ushort_t* ob  = (ushort_t*)d_out;
  ushort_t* xb   = ob;                    // bf16 x, a-region bytes [0,16.78M)
  ushort_t* q_ws = ob + A_ELEMS;          // bf16 q, a-region bytes [16.78M,33.55M)

  ushort_t* ws  = (ushort_t*)d_ws;        // 83.9 MB used
  ushort_t* wtq = ws;
  ushort_t* wtk = ws + W_ELEMS;
  ushort_t* wtv = ws + 2 * (size_t)W_ELEMS;
  ushort_t* wtd = ws + 3 * (size_t)W_ELEMS;
  ushort_t* attn_ws = ws + 4 * (size_t)W_ELEMS;            // bf16 [B,S,D]
  ushort_t* kb_ws   = attn_ws + (size_t)A_ELEMS;           // bf16 [B,H,S,hd]
  ushort_t* vt_ws   = attn_ws + 2 * (size_t)A_ELEMS;       // bf16 [B,H,hd,S]

  conv_x<<<4096, 256, 0, stream>>>(x, xb);
  trans_w<<<dim3(32, 32, 4), 256, 0, stream>>>(Wq, Wk, Wv, Wd,
                                               wtq, wtk, wtv, wtd);
  gemm_qkv<<<768, 512, 0, stream>>>(xb, wtq, wtk, wtv, bq, bk, bv,
                                    q_ws, k_out, v_out, kb_ws, vt_ws);
  attn_fwd<<<512, 256, 0, stream>>>(q_ws, kb_ws, vt_ws, attn_ws);
  gemm_proj<<<256, 512, 0, stream>>>(attn_ws, wtd, bd, a_out);
}